// Round 16
// baseline (535.300 us; speedup 1.0000x reference)
//
#include <hip/hip_runtime.h>
#include <hip/hip_bf16.h>
#include <hip/hip_fp16.h>
#include <math.h>

#define HH 4
#define CC 32
#define HC 128   // H*C
#define GG 64

typedef _Float16 f16x2 __attribute__((ext_vector_type(2)));
typedef _Float16 f16x8 __attribute__((ext_vector_type(8)));
typedef float f32x4 __attribute__((ext_vector_type(4)));

__device__ __forceinline__ f16x2 u2h(unsigned u) {
    union { unsigned u; f16x2 h; } x; x.u = u; return x.h;
}
__device__ __forceinline__ unsigned pkh(float a, float b) {
    __half2 h = __floats2half2_rn(a, b);
    union { __half2 h; unsigned u; } x; x.h = h; return x.u;
}
__device__ __forceinline__ f16x8 uq2h8(uint4 u) {
    union { uint4 u; f16x8 h; } x; x.u = u; return x.h;
}

// ---------------- bake W into MFMA fragments ----------------
// wfrag[(ct*KS + ks)*64 + lane] = 8 halves: W[ks*32 + (lane>>4)*8 + j][ct*16 + (lane&15)]
// ct 0-7: Wq, 8-15: Wk, 16-23: Wv, 24-25: Ws.
__device__ __forceinline__ void wfrag_item(const float* __restrict__ Wq, const float* __restrict__ Wk,
    const float* __restrict__ Wv, const float* __restrict__ Ws,
    uint4* __restrict__ wfrag, int KS, int idx)
{
    int lane = idx & 63;
    int t = idx >> 6;
    int ks = t % KS, ct = t / KS;
    int r = lane & 15, g = lane >> 4;
    const float* W; int c, stride;
    if (ct < 8)       { W = Wq; c = ct * 16 + r;        stride = HC; }
    else if (ct < 16) { W = Wk; c = (ct - 8) * 16 + r;  stride = HC; }
    else if (ct < 24) { W = Wv; c = (ct - 16) * 16 + r; stride = HC; }
    else              { W = Ws; c = (ct - 24) * 16 + r; stride = CC; }
    unsigned u[4];
    #pragma unroll
    for (int jj = 0; jj < 4; ++jj) {
        int k = ks * 32 + g * 8 + jj * 2;
        u[jj] = pkh(W[(size_t)k * stride + c], W[(size_t)(k + 1) * stride + c]);
    }
    wfrag[idx] = make_uint4(u[0], u[1], u[2], u[3]);
}

// ---------------- fused prep: x->fp16 + wfrag (both layers) + zero deg/sums ----------------
__global__ void prep_kernel(const float* __restrict__ x, unsigned* __restrict__ xh, int n4,
    const float* __restrict__ Wq1, const float* __restrict__ Wk1,
    const float* __restrict__ Wv1, const float* __restrict__ Ws1, uint4* __restrict__ wfrag1,
    const float* __restrict__ Wq2, const float* __restrict__ Wk2,
    const float* __restrict__ Wv2, const float* __restrict__ Ws2, uint4* __restrict__ wfrag2,
    int* __restrict__ deg, int N, float* __restrict__ sums)
{
    const int N1 = 26 * 4 * 64;     // layer 1 frags, KS=4
    const int N2 = 26 * 1 * 64;     // layer 2 frags, KS=1
    int i = blockIdx.x * 256 + threadIdx.x;
    if (i < n4) {
        float4 f = ((const float4*)x)[i];
        ((uint2*)xh)[i] = make_uint2(pkh(f.x, f.y), pkh(f.z, f.w));
        return;
    }
    i -= n4;
    if (i < N1) { wfrag_item(Wq1, Wk1, Wv1, Ws1, wfrag1, 4, i); return; }
    i -= N1;
    if (i < N2) { wfrag_item(Wq2, Wk2, Wv2, Ws2, wfrag2, 1, i); return; }
    i -= N2;
    if (i < N) { deg[i] = 0; return; }
    i -= N;
    if (i < GG * CC + GG) sums[i] = 0.f;
}

// ---------------- QKV + skip projection: MFMA GEMM (operand-swapped, r14 shape) ----------------
// grid = (ceil(N/64), 2); block 256 = 4 waves, each wave a 16-node strip.
// mfma(W-frag, x-frag): D = out[node = n0+(lane&15)][col = ct*16 + (lane>>4)*4 + reg]
// y=0: q (pre-scaled by (1/sqrt32)*log2e, half2 pairs) + skip (fp32)
// y=1: k+v -> kv4[node][32] uint4 {k01,k23,v01,v23} per channel-quad.
template<int KDIM>
__global__ __launch_bounds__(256) void qkv_mfma_kernel(
    const ushort* __restrict__ xh, const uint4* __restrict__ wfrag,
    const float* __restrict__ bq, const float* __restrict__ bk,
    const float* __restrict__ bv, const float* __restrict__ bs,
    unsigned* __restrict__ qh, uint4* __restrict__ kv4, float* __restrict__ skip,
    int N)
{
    constexpr int KS = KDIM / 32;
    const int lane = threadIdx.x & 63;
    const int wv = threadIdx.x >> 6;
    const int n0 = (blockIdx.x * 4 + wv) * 16;
    if (n0 >= N) return;
    const int r = lane & 15, g = lane >> 4;
    const int node = n0 + r;

    f16x8 a[KS];
    #pragma unroll
    for (int ks = 0; ks < KS; ++ks)
        a[ks] = uq2h8(*(const uint4*)&xh[(size_t)node * KDIM + ks * 32 + g * 8]);

    if (blockIdx.y == 0) {
        const float SC2 = 0.25500526806584186f;   // (1/sqrt(32)) * log2(e)
        f32x4 acc[10];
        #pragma unroll
        for (int i = 0; i < 10; ++i) acc[i] = (f32x4){0.f, 0.f, 0.f, 0.f};
        #pragma unroll
        for (int i = 0; i < 8; ++i)
            #pragma unroll
            for (int ks = 0; ks < KS; ++ks) {
                f16x8 w = uq2h8(wfrag[((size_t)i * KS + ks) * 64 + lane]);
                acc[i] = __builtin_amdgcn_mfma_f32_16x16x32_f16(w, a[ks], acc[i], 0, 0, 0);
            }
        #pragma unroll
        for (int i = 0; i < 2; ++i)
            #pragma unroll
            for (int ks = 0; ks < KS; ++ks) {
                f16x8 w = uq2h8(wfrag[((size_t)(24 + i) * KS + ks) * 64 + lane]);
                acc[8 + i] = __builtin_amdgcn_mfma_f32_16x16x32_f16(w, a[ks], acc[8 + i], 0, 0, 0);
            }
        if (node < N) {
            #pragma unroll
            for (int i = 0; i < 8; ++i) {
                float4 bb = *(const float4*)&bq[i * 16 + g * 4];
                uint2 o = make_uint2(pkh((acc[i][0] + bb.x) * SC2, (acc[i][1] + bb.y) * SC2),
                                     pkh((acc[i][2] + bb.z) * SC2, (acc[i][3] + bb.w) * SC2));
                *(uint2*)&qh[(size_t)node * 64 + i * 8 + g * 2] = o;
            }
            #pragma unroll
            for (int i = 0; i < 2; ++i) {
                float4 bb = *(const float4*)&bs[i * 16 + g * 4];
                float4 o = make_float4(acc[8 + i][0] + bb.x, acc[8 + i][1] + bb.y,
                                       acc[8 + i][2] + bb.z, acc[8 + i][3] + bb.w);
                *(float4*)&skip[(size_t)node * CC + i * 16 + g * 4] = o;
            }
        }
    } else {
        f32x4 acck[8], accv[8];
        #pragma unroll
        for (int i = 0; i < 8; ++i) { acck[i] = (f32x4){0.f,0.f,0.f,0.f}; accv[i] = (f32x4){0.f,0.f,0.f,0.f}; }
        #pragma unroll
        for (int i = 0; i < 8; ++i)
            #pragma unroll
            for (int ks = 0; ks < KS; ++ks) {
                f16x8 wk = uq2h8(wfrag[((size_t)(8 + i) * KS + ks) * 64 + lane]);
                acck[i] = __builtin_amdgcn_mfma_f32_16x16x32_f16(wk, a[ks], acck[i], 0, 0, 0);
                f16x8 wvf = uq2h8(wfrag[((size_t)(16 + i) * KS + ks) * 64 + lane]);
                accv[i] = __builtin_amdgcn_mfma_f32_16x16x32_f16(wvf, a[ks], accv[i], 0, 0, 0);
            }
        if (node < N) {
            #pragma unroll
            for (int i = 0; i < 8; ++i) {
                float4 bbk = *(const float4*)&bk[i * 16 + g * 4];
                float4 bbv = *(const float4*)&bv[i * 16 + g * 4];
                uint4 o;
                o.x = pkh(acck[i][0] + bbk.x, acck[i][1] + bbk.y);
                o.y = pkh(acck[i][2] + bbk.z, acck[i][3] + bbk.w);
                o.z = pkh(accv[i][0] + bbv.x, accv[i][1] + bbv.y);
                o.w = pkh(accv[i][2] + bbv.z, accv[i][3] + bbv.w);
                kv4[(size_t)node * 32 + i * 4 + g] = o;
            }
        }
    }
}

// ---------------- CSR build ----------------
__global__ void deg_kernel(const int* __restrict__ dst, int* __restrict__ deg, int E)
{
    int e = blockIdx.x * blockDim.x + threadIdx.x;
    if (e < E) atomicAdd(&deg[dst[e]], 1);
}

__global__ void bsum_kernel(const int* __restrict__ deg, int* __restrict__ bsum, int N)
{
    int base = blockIdx.x * 1024;
    int tid = threadIdx.x;  // 256
    int s = 0;
    for (int i = base + tid; i < base + 1024 && i < N; i += 256) s += deg[i];
    #pragma unroll
    for (int ofs = 32; ofs > 0; ofs >>= 1) s += __shfl_xor(s, ofs, 64);
    __shared__ int ws[4];
    int wid = tid >> 6;
    if ((tid & 63) == 0) ws[wid] = s;
    __syncthreads();
    if (tid == 0) bsum[blockIdx.x] = ws[0] + ws[1] + ws[2] + ws[3];
}

__global__ void bscan_kernel(int* __restrict__ bsum, int* __restrict__ off, int nb, int N)
{
    int i = threadIdx.x;   // 64
    int val = (i < nb) ? bsum[i] : 0;
    int v = val;
    #pragma unroll
    for (int ofs = 1; ofs < 64; ofs <<= 1) {
        int t = __shfl_up(v, ofs, 64);
        if (i >= ofs) v += t;
    }
    if (i < nb) bsum[i] = v - val;   // exclusive
    if (i == 63) off[N] = v;         // grand total
}

__global__ void scan2_kernel(const int* __restrict__ deg, const int* __restrict__ bsum,
                             int* __restrict__ off, int* __restrict__ cursor, int N)
{
    int base = blockIdx.x * 1024;
    int tid = threadIdx.x;          // 256
    int idx = base + tid * 4;
    int d0 = (idx     < N) ? deg[idx]     : 0;
    int d1 = (idx + 1 < N) ? deg[idx + 1] : 0;
    int d2 = (idx + 2 < N) ? deg[idx + 2] : 0;
    int d3 = (idx + 3 < N) ? deg[idx + 3] : 0;
    int tsum = d0 + d1 + d2 + d3;
    int v = tsum;
    int lane = tid & 63;
    #pragma unroll
    for (int ofs = 1; ofs < 64; ofs <<= 1) {
        int t = __shfl_up(v, ofs, 64);
        if (lane >= ofs) v += t;
    }
    __shared__ int wsum[4];
    int wid = tid >> 6;
    if (lane == 63) wsum[wid] = v;
    __syncthreads();
    int wbase = 0;
    for (int w = 0; w < wid; ++w) wbase += wsum[w];
    int excl = bsum[blockIdx.x] + wbase + (v - tsum);
    if (idx     < N) { off[idx]     = excl;                cursor[idx]     = excl; }
    if (idx + 1 < N) { off[idx + 1] = excl + d0;           cursor[idx + 1] = excl + d0; }
    if (idx + 2 < N) { off[idx + 2] = excl + d0 + d1;      cursor[idx + 2] = excl + d0 + d1; }
    if (idx + 3 < N) { off[idx + 3] = excl + d0 + d1 + d2; cursor[idx + 3] = excl + d0 + d1 + d2; }
}

__global__ void fill_kernel(const int* __restrict__ src, const int* __restrict__ dst,
                            int* __restrict__ cursor, int* __restrict__ esrc, int E)
{
    int e = blockIdx.x * blockDim.x + threadIdx.x;
    if (e < E) {
        int d = dst[e];
        int pos = atomicAdd(&cursor[d], 1);
        esrc[pos] = src[e];
    }
}

// ---------------- fused attention: 1 wave per node, 4-deep gather prefetch ----------------
// half = lane>>5 (edge parity), j = lane&31 (channel-quad, head = j>>3).
// kv4[n][32] uint4 = {k01,k23,v01,v23}. q pre-scaled so e = exp2(dot).
// MODE 1: relu + fp16-pair output to hout. MODE 0: fused graph-mean-pool (atomics into sums/cntf).
template<int MODE>
__global__ __launch_bounds__(128) void attn_kernel(const unsigned* __restrict__ qh,
    const uint4* __restrict__ kv4, const int* __restrict__ off, const int* __restrict__ esrc,
    const float* __restrict__ skip, void* __restrict__ hout, const int* __restrict__ batch,
    float* __restrict__ sums, float* __restrict__ cntf, int N)
{
    const int wave = threadIdx.x >> 6;
    const int lane = threadIdx.x & 63;
    const int n = blockIdx.x * 2 + wave;
    if (n >= N) return;
    const int half = lane >> 5;
    const int j = lane & 31;

    uint2 qv = *(const uint2*)&qh[(size_t)n * 64 + j * 2];
    f16x2 q01 = u2h(qv.x), q23 = u2h(qv.y);

    int beg = __builtin_amdgcn_readfirstlane(off[n]);
    int end = __builtin_amdgcn_readfirstlane(off[n + 1]);

    float lsum = 0.f, a0 = 0.f, a1 = 0.f, a2 = 0.f, a3 = 0.f;

    auto compute = [&](uint4 raw) {
        f16x2 k01 = u2h(raw.x), k23 = u2h(raw.y);
        f16x2 v01 = u2h(raw.z), v23 = u2h(raw.w);
#if defined(__has_builtin) && __has_builtin(__builtin_amdgcn_fdot2)
        float d = __builtin_amdgcn_fdot2(q01, k01,
                    __builtin_amdgcn_fdot2(q23, k23, 0.f, false), false);
#else
        float d = (float)q01.x*(float)k01.x + (float)q01.y*(float)k01.y
                + (float)q23.x*(float)k23.x + (float)q23.y*(float)k23.y;
#endif
        d += __shfl_xor(d, 1, 8);
        d += __shfl_xor(d, 2, 8);
        d += __shfl_xor(d, 4, 8);
        float e = exp2f(d);
        lsum += e;
        a0 = fmaf(e, (float)v01.x, a0);
        a1 = fmaf(e, (float)v01.y, a1);
        a2 = fmaf(e, (float)v23.x, a2);
        a3 = fmaf(e, (float)v23.y, a3);
    };
    auto ld = [&](int p2) -> uint4 {           // gathers edge p2+half
        return kv4[(size_t)esrc[p2 + half] * 32 + j];
    };

    int p = beg;
    if (p + 8 <= end) {
        uint4 c0 = ld(p), c1 = ld(p + 2), c2 = ld(p + 4), c3 = ld(p + 6);
        p += 8;
        for (; p + 8 <= end; p += 8) {
            uint4 n0 = ld(p), n1 = ld(p + 2), n2 = ld(p + 4), n3 = ld(p + 6);
            compute(c0); compute(c1); compute(c2); compute(c3);
            c0 = n0; c1 = n1; c2 = n2; c3 = n3;
        }
        compute(c0); compute(c1); compute(c2); compute(c3);
    }
    for (; p < end; p += 2) {
        int idx = p + half;
        int sidx = (idx >= end) ? end - 1 : idx;
        uint4 raw = kv4[(size_t)esrc[sidx] * 32 + j];
        f16x2 k01 = u2h(raw.x), k23 = u2h(raw.y);
        f16x2 v01 = u2h(raw.z), v23 = u2h(raw.w);
#if defined(__has_builtin) && __has_builtin(__builtin_amdgcn_fdot2)
        float d = __builtin_amdgcn_fdot2(q01, k01,
                    __builtin_amdgcn_fdot2(q23, k23, 0.f, false), false);
#else
        float d = (float)q01.x*(float)k01.x + (float)q01.y*(float)k01.y
                + (float)q23.x*(float)k23.x + (float)q23.y*(float)k23.y;
#endif
        d += __shfl_xor(d, 1, 8);
        d += __shfl_xor(d, 2, 8);
        d += __shfl_xor(d, 4, 8);
        float e = exp2f(d);
        if (idx >= end) e = 0.f;
        lsum += e;
        a0 = fmaf(e, (float)v01.x, a0);
        a1 = fmaf(e, (float)v01.y, a1);
        a2 = fmaf(e, (float)v23.x, a2);
        a3 = fmaf(e, (float)v23.y, a3);
    }

    // combine edge-halves
    lsum += __shfl_xor(lsum, 32);
    a0 += __shfl_xor(a0, 32);
    a1 += __shfl_xor(a1, 32);
    a2 += __shfl_xor(a2, 32);
    a3 += __shfl_xor(a3, 32);

    // per-head normalize, then head-average
    float inv = 1.f / (lsum + 1e-16f);
    float r0 = a0 * inv, r1 = a1 * inv, r2 = a2 * inv, r3 = a3 * inv;
    r0 += __shfl_xor(r0, 8, 32);  r0 += __shfl_xor(r0, 16, 32);
    r1 += __shfl_xor(r1, 8, 32);  r1 += __shfl_xor(r1, 16, 32);
    r2 += __shfl_xor(r2, 8, 32);  r2 += __shfl_xor(r2, 16, 32);
    r3 += __shfl_xor(r3, 8, 32);  r3 += __shfl_xor(r3, 16, 32);

    if (lane < 8) {
        float4 sk = *(const float4*)&skip[(size_t)n * CC + lane * 4];
        float o0 = 0.25f * r0 + sk.x;
        float o1 = 0.25f * r1 + sk.y;
        float o2 = 0.25f * r2 + sk.z;
        float o3 = 0.25f * r3 + sk.w;
        if (MODE) {
            o0 = fmaxf(o0, 0.f); o1 = fmaxf(o1, 0.f);
            o2 = fmaxf(o2, 0.f); o3 = fmaxf(o3, 0.f);
            *(uint2*)&((unsigned*)hout)[(size_t)n * 16 + lane * 2] =
                make_uint2(pkh(o0, o1), pkh(o2, o3));
        } else {
            // fused graph-mean pool: accumulate directly into per-graph sums
            int g = batch[n];
            float* sg = &sums[g * CC + lane * 4];
            unsafeAtomicAdd(&sg[0], o0);
            unsafeAtomicAdd(&sg[1], o1);
            unsafeAtomicAdd(&sg[2], o2);
            unsafeAtomicAdd(&sg[3], o3);
            if (lane == 0) unsafeAtomicAdd(&cntf[g], 1.f);
        }
    }
}

// ---------------- final linear ----------------
__global__ void final_lin_kernel(const float* __restrict__ sums, const float* __restrict__ cntf,
    const float* __restrict__ Wlin, const float* __restrict__ blin, float* __restrict__ out)
{
    int g = blockIdx.x;        // 64
    int j = threadIdx.x;       // 16
    float cnt = fmaxf(cntf[g], 1.0f);
    float acc = 0.f;
    #pragma unroll
    for (int c = 0; c < CC; ++c)
        acc += (sums[g * CC + c] / cnt) * Wlin[c * 16 + j];
    out[g * 16 + j] = acc + blin[j];
}

extern "C" void kernel_launch(void* const* d_in, const int* in_sizes, int n_in,
                              void* d_out, int out_size, void* d_ws, size_t ws_size,
                              hipStream_t stream) {
    const float* x     = (const float*)d_in[0];
    const int*   ei    = (const int*)d_in[1];
    const int*   batch = (const int*)d_in[2];
    const float* Wq1 = (const float*)d_in[3],  *bq1 = (const float*)d_in[4];
    const float* Wk1 = (const float*)d_in[5],  *bk1 = (const float*)d_in[6];
    const float* Wv1 = (const float*)d_in[7],  *bv1 = (const float*)d_in[8];
    const float* Ws1 = (const float*)d_in[9],  *bs1 = (const float*)d_in[10];
    const float* Wq2 = (const float*)d_in[11], *bq2 = (const float*)d_in[12];
    const float* Wk2 = (const float*)d_in[13], *bk2 = (const float*)d_in[14];
    const float* Wv2 = (const float*)d_in[15], *bv2 = (const float*)d_in[16];
    const float* Ws2 = (const float*)d_in[17], *bs2 = (const float*)d_in[18];
    const float* Wlin = (const float*)d_in[19], *blin = (const float*)d_in[20];

    const int N = in_sizes[0] / 128;
    const int E = in_sizes[1] / 2;
    const int* src = ei;
    const int* dstp = ei + E;
    const int NB = (N + 1023) / 1024;
    const int Npad = (N + 63) & ~63;

    // workspace carve (256B aligned)
    char* wp = (char*)d_ws;
    auto alloc = [&](size_t bytes) -> void* {
        void* p = wp;
        wp += (bytes + 255) & ~(size_t)255;
        return p;
    };
    unsigned* qh   = (unsigned*)alloc((size_t)N * 64 * 4);    // q half2 pairs (pre-scaled)
    uint4* kv4     = (uint4*)alloc((size_t)N * 32 * 16);      // {k01,k23,v01,v23} per quad
    float* skip    = (float*)alloc((size_t)N * CC * 4);
    unsigned* h1h  = (unsigned*)alloc((size_t)Npad * 16 * 4); // h1 fp16 pairs [N][16]
    ushort* xh     = (ushort*)alloc((size_t)Npad * HC * 2);   // x fp16
    uint4* wfrag1  = (uint4*)alloc((size_t)26 * 4 * 64 * 16);
    uint4* wfrag2  = (uint4*)alloc((size_t)26 * 1 * 64 * 16);
    int* deg    = (int*)alloc((size_t)N * 4);
    int* off    = (int*)alloc((size_t)(N + 1) * 4);
    int* cursor = (int*)alloc((size_t)N * 4);
    int* esrc   = (int*)alloc((size_t)E * 4);
    int* bsum   = (int*)alloc((size_t)((NB + 63) & ~63) * 4);
    float* sums = (float*)alloc((size_t)GG * CC * 4);   // contiguous with cntf
    float* cntf = (float*)alloc((size_t)GG * 4);

    // ---- fused prep: x->fp16, wfrags, zero deg + sums/cntf ----
    const int n4 = N * HC / 4;
    const int prep_total = n4 + 26 * 5 * 64 + N + GG * CC + GG;
    prep_kernel<<<(prep_total + 255) / 256, 256, 0, stream>>>(
        x, (unsigned*)xh, n4,
        Wq1, Wk1, Wv1, Ws1, wfrag1, Wq2, Wk2, Wv2, Ws2, wfrag2,
        deg, N, sums);

    // ---- CSR build (once; shared by both layers) ----
    deg_kernel<<<(E + 255) / 256, 256, 0, stream>>>(dstp, deg, E);
    bsum_kernel<<<NB, 256, 0, stream>>>(deg, bsum, N);
    bscan_kernel<<<1, 64, 0, stream>>>(bsum, off, NB, N);
    scan2_kernel<<<NB, 256, 0, stream>>>(deg, bsum, off, cursor, N);
    fill_kernel<<<(E + 255) / 256, 256, 0, stream>>>(src, dstp, cursor, esrc, E);

    dim3 ggrid((N + 63) / 64, 2);
    dim3 agrid((N + 1) / 2);

    // ---- layer 1 ----
    qkv_mfma_kernel<128><<<ggrid, 256, 0, stream>>>(xh, wfrag1, bq1, bk1, bv1, bs1,
                                                    qh, kv4, skip, N);
    attn_kernel<1><<<agrid, 128, 0, stream>>>(qh, kv4, off, esrc, skip, h1h,
                                              batch, sums, cntf, N);

    // ---- layer 2 (attn fused with graph-mean pool) ----
    qkv_mfma_kernel<32><<<ggrid, 256, 0, stream>>>((const ushort*)h1h, wfrag2, bq2, bk2, bv2, bs2,
                                                   qh, kv4, skip, N);
    attn_kernel<0><<<agrid, 128, 0, stream>>>(qh, kv4, off, esrc, skip, nullptr,
                                              batch, sums, cntf, N);

    // ---- final linear ----
    final_lin_kernel<<<GG, 16, 0, stream>>>(sums, cntf, Wlin, blin, (float*)d_out);
}

// Round 17
// 231.132 us; speedup vs baseline: 2.3160x; 2.3160x over previous
//
#include <hip/hip_runtime.h>
#include <hip/hip_bf16.h>
#include <hip/hip_fp16.h>
#include <math.h>

#define HH 4
#define CC 32
#define HC 128   // H*C
#define GG 64

typedef _Float16 f16x2 __attribute__((ext_vector_type(2)));
typedef _Float16 f16x8 __attribute__((ext_vector_type(8)));
typedef float f32x4 __attribute__((ext_vector_type(4)));

__device__ __forceinline__ f16x2 u2h(unsigned u) {
    union { unsigned u; f16x2 h; } x; x.u = u; return x.h;
}
__device__ __forceinline__ unsigned pkh(float a, float b) {
    __half2 h = __floats2half2_rn(a, b);
    union { __half2 h; unsigned u; } x; x.h = h; return x.u;
}
__device__ __forceinline__ f16x8 uq2h8(uint4 u) {
    union { uint4 u; f16x8 h; } x; x.u = u; return x.h;
}

// ---------------- bake W into MFMA fragments ----------------
// wfrag[(ct*KS + ks)*64 + lane] = 8 halves: W[ks*32 + (lane>>4)*8 + j][ct*16 + (lane&15)]
// ct 0-7: Wq, 8-15: Wk, 16-23: Wv, 24-25: Ws.
__device__ __forceinline__ void wfrag_item(const float* __restrict__ Wq, const float* __restrict__ Wk,
    const float* __restrict__ Wv, const float* __restrict__ Ws,
    uint4* __restrict__ wfrag, int KS, int idx)
{
    int lane = idx & 63;
    int t = idx >> 6;
    int ks = t % KS, ct = t / KS;
    int r = lane & 15, g = lane >> 4;
    const float* W; int c, stride;
    if (ct < 8)       { W = Wq; c = ct * 16 + r;        stride = HC; }
    else if (ct < 16) { W = Wk; c = (ct - 8) * 16 + r;  stride = HC; }
    else if (ct < 24) { W = Wv; c = (ct - 16) * 16 + r; stride = HC; }
    else              { W = Ws; c = (ct - 24) * 16 + r; stride = CC; }
    unsigned u[4];
    #pragma unroll
    for (int jj = 0; jj < 4; ++jj) {
        int k = ks * 32 + g * 8 + jj * 2;
        u[jj] = pkh(W[(size_t)k * stride + c], W[(size_t)(k + 1) * stride + c]);
    }
    wfrag[idx] = make_uint4(u[0], u[1], u[2], u[3]);
}

// ---------------- fused prep: x->fp16 + wfrag (both layers) + zero deg/sums ----------------
__global__ void prep_kernel(const float* __restrict__ x, unsigned* __restrict__ xh, int n4,
    const float* __restrict__ Wq1, const float* __restrict__ Wk1,
    const float* __restrict__ Wv1, const float* __restrict__ Ws1, uint4* __restrict__ wfrag1,
    const float* __restrict__ Wq2, const float* __restrict__ Wk2,
    const float* __restrict__ Wv2, const float* __restrict__ Ws2, uint4* __restrict__ wfrag2,
    int* __restrict__ deg, int N, float* __restrict__ sums)
{
    const int N1 = 26 * 4 * 64;     // layer 1 frags, KS=4
    const int N2 = 26 * 1 * 64;     // layer 2 frags, KS=1
    int i = blockIdx.x * 256 + threadIdx.x;
    if (i < n4) {
        float4 f = ((const float4*)x)[i];
        ((uint2*)xh)[i] = make_uint2(pkh(f.x, f.y), pkh(f.z, f.w));
        return;
    }
    i -= n4;
    if (i < N1) { wfrag_item(Wq1, Wk1, Wv1, Ws1, wfrag1, 4, i); return; }
    i -= N1;
    if (i < N2) { wfrag_item(Wq2, Wk2, Wv2, Ws2, wfrag2, 1, i); return; }
    i -= N2;
    if (i < N) { deg[i] = 0; return; }
    i -= N;
    if (i < GG * CC + GG) sums[i] = 0.f;
}

// ---------------- QKV + skip projection: MFMA GEMM (operand-swapped) ----------------
// grid = (ceil(N/64), 2); block 256 = 4 waves, each wave a 16-node strip.
// mfma(W-frag, x-frag): D = out[node = n0+(lane&15)][col = ct*16 + (lane>>4)*4 + reg]
// y=0: q (pre-scaled by (1/sqrt32)*log2e, half2 pairs) + skip (fp32)
// y=1: k+v -> kv4[node][32] uint4 {k01,k23,v01,v23} per channel-quad.
template<int KDIM>
__global__ __launch_bounds__(256) void qkv_mfma_kernel(
    const ushort* __restrict__ xh, const uint4* __restrict__ wfrag,
    const float* __restrict__ bq, const float* __restrict__ bk,
    const float* __restrict__ bv, const float* __restrict__ bs,
    unsigned* __restrict__ qh, uint4* __restrict__ kv4, float* __restrict__ skip,
    int N)
{
    constexpr int KS = KDIM / 32;
    const int lane = threadIdx.x & 63;
    const int wv = threadIdx.x >> 6;
    const int n0 = (blockIdx.x * 4 + wv) * 16;
    if (n0 >= N) return;
    const int r = lane & 15, g = lane >> 4;
    const int node = n0 + r;

    f16x8 a[KS];
    #pragma unroll
    for (int ks = 0; ks < KS; ++ks)
        a[ks] = uq2h8(*(const uint4*)&xh[(size_t)node * KDIM + ks * 32 + g * 8]);

    if (blockIdx.y == 0) {
        const float SC2 = 0.25500526806584186f;   // (1/sqrt(32)) * log2(e)
        f32x4 acc[10];
        #pragma unroll
        for (int i = 0; i < 10; ++i) acc[i] = (f32x4){0.f, 0.f, 0.f, 0.f};
        #pragma unroll
        for (int i = 0; i < 8; ++i)
            #pragma unroll
            for (int ks = 0; ks < KS; ++ks) {
                f16x8 w = uq2h8(wfrag[((size_t)i * KS + ks) * 64 + lane]);
                acc[i] = __builtin_amdgcn_mfma_f32_16x16x32_f16(w, a[ks], acc[i], 0, 0, 0);
            }
        #pragma unroll
        for (int i = 0; i < 2; ++i)
            #pragma unroll
            for (int ks = 0; ks < KS; ++ks) {
                f16x8 w = uq2h8(wfrag[((size_t)(24 + i) * KS + ks) * 64 + lane]);
                acc[8 + i] = __builtin_amdgcn_mfma_f32_16x16x32_f16(w, a[ks], acc[8 + i], 0, 0, 0);
            }
        if (node < N) {
            #pragma unroll
            for (int i = 0; i < 8; ++i) {
                float4 bb = *(const float4*)&bq[i * 16 + g * 4];
                uint2 o = make_uint2(pkh((acc[i][0] + bb.x) * SC2, (acc[i][1] + bb.y) * SC2),
                                     pkh((acc[i][2] + bb.z) * SC2, (acc[i][3] + bb.w) * SC2));
                *(uint2*)&qh[(size_t)node * 64 + i * 8 + g * 2] = o;
            }
            #pragma unroll
            for (int i = 0; i < 2; ++i) {
                float4 bb = *(const float4*)&bs[i * 16 + g * 4];
                float4 o = make_float4(acc[8 + i][0] + bb.x, acc[8 + i][1] + bb.y,
                                       acc[8 + i][2] + bb.z, acc[8 + i][3] + bb.w);
                *(float4*)&skip[(size_t)node * CC + i * 16 + g * 4] = o;
            }
        }
    } else {
        f32x4 acck[8], accv[8];
        #pragma unroll
        for (int i = 0; i < 8; ++i) { acck[i] = (f32x4){0.f,0.f,0.f,0.f}; accv[i] = (f32x4){0.f,0.f,0.f,0.f}; }
        #pragma unroll
        for (int i = 0; i < 8; ++i)
            #pragma unroll
            for (int ks = 0; ks < KS; ++ks) {
                f16x8 wk = uq2h8(wfrag[((size_t)(8 + i) * KS + ks) * 64 + lane]);
                acck[i] = __builtin_amdgcn_mfma_f32_16x16x32_f16(wk, a[ks], acck[i], 0, 0, 0);
                f16x8 wvf = uq2h8(wfrag[((size_t)(16 + i) * KS + ks) * 64 + lane]);
                accv[i] = __builtin_amdgcn_mfma_f32_16x16x32_f16(wvf, a[ks], accv[i], 0, 0, 0);
            }
        if (node < N) {
            #pragma unroll
            for (int i = 0; i < 8; ++i) {
                float4 bbk = *(const float4*)&bk[i * 16 + g * 4];
                float4 bbv = *(const float4*)&bv[i * 16 + g * 4];
                uint4 o;
                o.x = pkh(acck[i][0] + bbk.x, acck[i][1] + bbk.y);
                o.y = pkh(acck[i][2] + bbk.z, acck[i][3] + bbk.w);
                o.z = pkh(accv[i][0] + bbv.x, accv[i][1] + bbv.y);
                o.w = pkh(accv[i][2] + bbv.z, accv[i][3] + bbv.w);
                kv4[(size_t)node * 32 + i * 4 + g] = o;
            }
        }
    }
}

// ---------------- CSR build ----------------
__global__ void deg_kernel(const int* __restrict__ dst, int* __restrict__ deg, int E)
{
    int e = blockIdx.x * blockDim.x + threadIdx.x;
    if (e < E) atomicAdd(&deg[dst[e]], 1);
}

__global__ void bsum_kernel(const int* __restrict__ deg, int* __restrict__ bsum, int N)
{
    int base = blockIdx.x * 1024;
    int tid = threadIdx.x;  // 256
    int s = 0;
    for (int i = base + tid; i < base + 1024 && i < N; i += 256) s += deg[i];
    #pragma unroll
    for (int ofs = 32; ofs > 0; ofs >>= 1) s += __shfl_xor(s, ofs, 64);
    __shared__ int ws[4];
    int wid = tid >> 6;
    if ((tid & 63) == 0) ws[wid] = s;
    __syncthreads();
    if (tid == 0) bsum[blockIdx.x] = ws[0] + ws[1] + ws[2] + ws[3];
}

__global__ void bscan_kernel(int* __restrict__ bsum, int* __restrict__ off, int nb, int N)
{
    int i = threadIdx.x;   // 64
    int val = (i < nb) ? bsum[i] : 0;
    int v = val;
    #pragma unroll
    for (int ofs = 1; ofs < 64; ofs <<= 1) {
        int t = __shfl_up(v, ofs, 64);
        if (i >= ofs) v += t;
    }
    if (i < nb) bsum[i] = v - val;   // exclusive
    if (i == 63) off[N] = v;         // grand total
}

__global__ void scan2_kernel(const int* __restrict__ deg, const int* __restrict__ bsum,
                             int* __restrict__ off, int* __restrict__ cursor, int N)
{
    int base = blockIdx.x * 1024;
    int tid = threadIdx.x;          // 256
    int idx = base + tid * 4;
    int d0 = (idx     < N) ? deg[idx]     : 0;
    int d1 = (idx + 1 < N) ? deg[idx + 1] : 0;
    int d2 = (idx + 2 < N) ? deg[idx + 2] : 0;
    int d3 = (idx + 3 < N) ? deg[idx + 3] : 0;
    int tsum = d0 + d1 + d2 + d3;
    int v = tsum;
    int lane = tid & 63;
    #pragma unroll
    for (int ofs = 1; ofs < 64; ofs <<= 1) {
        int t = __shfl_up(v, ofs, 64);
        if (lane >= ofs) v += t;
    }
    __shared__ int wsum[4];
    int wid = tid >> 6;
    if (lane == 63) wsum[wid] = v;
    __syncthreads();
    int wbase = 0;
    for (int w = 0; w < wid; ++w) wbase += wsum[w];
    int excl = bsum[blockIdx.x] + wbase + (v - tsum);
    if (idx     < N) { off[idx]     = excl;                cursor[idx]     = excl; }
    if (idx + 1 < N) { off[idx + 1] = excl + d0;           cursor[idx + 1] = excl + d0; }
    if (idx + 2 < N) { off[idx + 2] = excl + d0 + d1;      cursor[idx + 2] = excl + d0 + d1; }
    if (idx + 3 < N) { off[idx + 3] = excl + d0 + d1 + d2; cursor[idx + 3] = excl + d0 + d1 + d2; }
}

__global__ void fill_kernel(const int* __restrict__ src, const int* __restrict__ dst,
                            int* __restrict__ cursor, int* __restrict__ esrc, int E)
{
    int e = blockIdx.x * blockDim.x + threadIdx.x;
    if (e < E) {
        int d = dst[e];
        int pos = atomicAdd(&cursor[d], 1);
        esrc[pos] = src[e];
    }
}

// ---------------- fused attention: 1 wave per node, 4-deep gather prefetch ----------------
// half = lane>>5 (edge parity), j = lane&31 (channel-quad, head = j>>3).
// kv4[n][32] uint4 = {k01,k23,v01,v23}. q pre-scaled so e = exp2(dot).
template<int MODE>
__global__ __launch_bounds__(128) void attn_kernel(const unsigned* __restrict__ qh,
    const uint4* __restrict__ kv4, const int* __restrict__ off, const int* __restrict__ esrc,
    const float* __restrict__ skip, void* __restrict__ hout, int N)
{
    const int wave = threadIdx.x >> 6;
    const int lane = threadIdx.x & 63;
    const int n = blockIdx.x * 2 + wave;
    if (n >= N) return;
    const int half = lane >> 5;
    const int j = lane & 31;

    uint2 qv = *(const uint2*)&qh[(size_t)n * 64 + j * 2];
    f16x2 q01 = u2h(qv.x), q23 = u2h(qv.y);

    int beg = __builtin_amdgcn_readfirstlane(off[n]);
    int end = __builtin_amdgcn_readfirstlane(off[n + 1]);

    float lsum = 0.f, a0 = 0.f, a1 = 0.f, a2 = 0.f, a3 = 0.f;

    auto compute = [&](uint4 raw) {
        f16x2 k01 = u2h(raw.x), k23 = u2h(raw.y);
        f16x2 v01 = u2h(raw.z), v23 = u2h(raw.w);
#if defined(__has_builtin) && __has_builtin(__builtin_amdgcn_fdot2)
        float d = __builtin_amdgcn_fdot2(q01, k01,
                    __builtin_amdgcn_fdot2(q23, k23, 0.f, false), false);
#else
        float d = (float)q01.x*(float)k01.x + (float)q01.y*(float)k01.y
                + (float)q23.x*(float)k23.x + (float)q23.y*(float)k23.y;
#endif
        d += __shfl_xor(d, 1, 8);
        d += __shfl_xor(d, 2, 8);
        d += __shfl_xor(d, 4, 8);
        float e = exp2f(d);
        lsum += e;
        a0 = fmaf(e, (float)v01.x, a0);
        a1 = fmaf(e, (float)v01.y, a1);
        a2 = fmaf(e, (float)v23.x, a2);
        a3 = fmaf(e, (float)v23.y, a3);
    };
    auto ld = [&](int p2) -> uint4 {           // gathers edge p2+half
        return kv4[(size_t)esrc[p2 + half] * 32 + j];
    };

    int p = beg;
    if (p + 8 <= end) {
        uint4 c0 = ld(p), c1 = ld(p + 2), c2 = ld(p + 4), c3 = ld(p + 6);
        p += 8;
        for (; p + 8 <= end; p += 8) {
            uint4 n0 = ld(p), n1 = ld(p + 2), n2 = ld(p + 4), n3 = ld(p + 6);
            compute(c0); compute(c1); compute(c2); compute(c3);
            c0 = n0; c1 = n1; c2 = n2; c3 = n3;
        }
        compute(c0); compute(c1); compute(c2); compute(c3);
    }
    for (; p < end; p += 2) {
        int idx = p + half;
        int sidx = (idx >= end) ? end - 1 : idx;
        uint4 raw = kv4[(size_t)esrc[sidx] * 32 + j];
        f16x2 k01 = u2h(raw.x), k23 = u2h(raw.y);
        f16x2 v01 = u2h(raw.z), v23 = u2h(raw.w);
#if defined(__has_builtin) && __has_builtin(__builtin_amdgcn_fdot2)
        float d = __builtin_amdgcn_fdot2(q01, k01,
                    __builtin_amdgcn_fdot2(q23, k23, 0.f, false), false);
#else
        float d = (float)q01.x*(float)k01.x + (float)q01.y*(float)k01.y
                + (float)q23.x*(float)k23.x + (float)q23.y*(float)k23.y;
#endif
        d += __shfl_xor(d, 1, 8);
        d += __shfl_xor(d, 2, 8);
        d += __shfl_xor(d, 4, 8);
        float e = exp2f(d);
        if (idx >= end) e = 0.f;
        lsum += e;
        a0 = fmaf(e, (float)v01.x, a0);
        a1 = fmaf(e, (float)v01.y, a1);
        a2 = fmaf(e, (float)v23.x, a2);
        a3 = fmaf(e, (float)v23.y, a3);
    }

    // combine edge-halves
    lsum += __shfl_xor(lsum, 32);
    a0 += __shfl_xor(a0, 32);
    a1 += __shfl_xor(a1, 32);
    a2 += __shfl_xor(a2, 32);
    a3 += __shfl_xor(a3, 32);

    // per-head normalize, then head-average
    float inv = 1.f / (lsum + 1e-16f);
    float r0 = a0 * inv, r1 = a1 * inv, r2 = a2 * inv, r3 = a3 * inv;
    r0 += __shfl_xor(r0, 8, 32);  r0 += __shfl_xor(r0, 16, 32);
    r1 += __shfl_xor(r1, 8, 32);  r1 += __shfl_xor(r1, 16, 32);
    r2 += __shfl_xor(r2, 8, 32);  r2 += __shfl_xor(r2, 16, 32);
    r3 += __shfl_xor(r3, 8, 32);  r3 += __shfl_xor(r3, 16, 32);

    if (lane < 8) {
        float4 sk = *(const float4*)&skip[(size_t)n * CC + lane * 4];
        float o0 = 0.25f * r0 + sk.x;
        float o1 = 0.25f * r1 + sk.y;
        float o2 = 0.25f * r2 + sk.z;
        float o3 = 0.25f * r3 + sk.w;
        if (MODE) {
            o0 = fmaxf(o0, 0.f); o1 = fmaxf(o1, 0.f);
            o2 = fmaxf(o2, 0.f); o3 = fmaxf(o3, 0.f);
            *(uint2*)&((unsigned*)hout)[(size_t)n * 16 + lane * 2] =
                make_uint2(pkh(o0, o1), pkh(o2, o3));
        } else {
            *(float4*)&((float*)hout)[(size_t)n * CC + lane * 4] =
                make_float4(o0, o1, o2, o3);
        }
    }
}

// ---------------- global mean pool (sorted-run accumulation) ----------------
__global__ void pool_kernel(const float* __restrict__ h, const int* __restrict__ batch,
    float* __restrict__ sums, float* __restrict__ cntf, int N)
{
    int c = threadIdx.x & 31;
    int tn = threadIdx.x >> 5;            // 0..7
    int n0 = blockIdx.x * 256;
    int nend = (n0 + 256 < N) ? n0 + 256 : N;
    float acc = 0.f, cnt = 0.f;
    int curg = -1;
    for (int n = n0 + tn; n < nend; n += 8) {
        int g = batch[n];
        if (g != curg) {
            if (curg >= 0) {
                unsafeAtomicAdd(&sums[curg * CC + c], acc);
                if (c == 0) unsafeAtomicAdd(&cntf[curg], cnt);
            }
            acc = 0.f; cnt = 0.f; curg = g;
        }
        acc += h[(size_t)n * CC + c];
        cnt += 1.f;
    }
    if (curg >= 0) {
        unsafeAtomicAdd(&sums[curg * CC + c], acc);
        if (c == 0) unsafeAtomicAdd(&cntf[curg], cnt);
    }
}

// ---------------- final linear ----------------
__global__ void final_lin_kernel(const float* __restrict__ sums, const float* __restrict__ cntf,
    const float* __restrict__ Wlin, const float* __restrict__ blin, float* __restrict__ out)
{
    int g = blockIdx.x;        // 64
    int j = threadIdx.x;       // 16
    float cnt = fmaxf(cntf[g], 1.0f);
    float acc = 0.f;
    #pragma unroll
    for (int c = 0; c < CC; ++c)
        acc += (sums[g * CC + c] / cnt) * Wlin[c * 16 + j];
    out[g * 16 + j] = acc + blin[j];
}

extern "C" void kernel_launch(void* const* d_in, const int* in_sizes, int n_in,
                              void* d_out, int out_size, void* d_ws, size_t ws_size,
                              hipStream_t stream) {
    const float* x     = (const float*)d_in[0];
    const int*   ei    = (const int*)d_in[1];
    const int*   batch = (const int*)d_in[2];
    const float* Wq1 = (const float*)d_in[3],  *bq1 = (const float*)d_in[4];
    const float* Wk1 = (const float*)d_in[5],  *bk1 = (const float*)d_in[6];
    const float* Wv1 = (const float*)d_in[7],  *bv1 = (const float*)d_in[8];
    const float* Ws1 = (const float*)d_in[9],  *bs1 = (const float*)d_in[10];
    const float* Wq2 = (const float*)d_in[11], *bq2 = (const float*)d_in[12];
    const float* Wk2 = (const float*)d_in[13], *bk2 = (const float*)d_in[14];
    const float* Wv2 = (const float*)d_in[15], *bv2 = (const float*)d_in[16];
    const float* Ws2 = (const float*)d_in[17], *bs2 = (const float*)d_in[18];
    const float* Wlin = (const float*)d_in[19], *blin = (const float*)d_in[20];

    const int N = in_sizes[0] / 128;
    const int E = in_sizes[1] / 2;
    const int* src = ei;
    const int* dstp = ei + E;
    const int NB = (N + 1023) / 1024;
    const int Npad = (N + 63) & ~63;

    // workspace carve (256B aligned)
    char* wp = (char*)d_ws;
    auto alloc = [&](size_t bytes) -> void* {
        void* p = wp;
        wp += (bytes + 255) & ~(size_t)255;
        return p;
    };
    unsigned* qh   = (unsigned*)alloc((size_t)N * 64 * 4);    // q half2 pairs (pre-scaled)
    uint4* kv4     = (uint4*)alloc((size_t)N * 32 * 16);      // {k01,k23,v01,v23} per quad
    float* skip    = (float*)alloc((size_t)N * CC * 4);
    unsigned* h1h  = (unsigned*)alloc((size_t)Npad * 16 * 4); // h1 fp16 pairs [N][16]
    float* h2      = (float*)alloc((size_t)N * CC * 4);
    ushort* xh     = (ushort*)alloc((size_t)Npad * HC * 2);   // x fp16
    uint4* wfrag1  = (uint4*)alloc((size_t)26 * 4 * 64 * 16);
    uint4* wfrag2  = (uint4*)alloc((size_t)26 * 1 * 64 * 16);
    int* deg    = (int*)alloc((size_t)N * 4);
    int* off    = (int*)alloc((size_t)(N + 1) * 4);
    int* cursor = (int*)alloc((size_t)N * 4);
    int* esrc   = (int*)alloc((size_t)E * 4);
    int* bsum   = (int*)alloc((size_t)((NB + 63) & ~63) * 4);
    float* sums = (float*)alloc((size_t)GG * CC * 4);   // contiguous with cntf
    float* cntf = (float*)alloc((size_t)GG * 4);

    // ---- fused prep: x->fp16, wfrags, zero deg + sums/cntf ----
    const int n4 = N * HC / 4;
    const int prep_total = n4 + 26 * 5 * 64 + N + GG * CC + GG;
    prep_kernel<<<(prep_total + 255) / 256, 256, 0, stream>>>(
        x, (unsigned*)xh, n4,
        Wq1, Wk1, Wv1, Ws1, wfrag1, Wq2, Wk2, Wv2, Ws2, wfrag2,
        deg, N, sums);

    // ---- CSR build (once; shared by both layers) ----
    deg_kernel<<<(E + 255) / 256, 256, 0, stream>>>(dstp, deg, E);
    bsum_kernel<<<NB, 256, 0, stream>>>(deg, bsum, N);
    bscan_kernel<<<1, 64, 0, stream>>>(bsum, off, NB, N);
    scan2_kernel<<<NB, 256, 0, stream>>>(deg, bsum, off, cursor, N);
    fill_kernel<<<(E + 255) / 256, 256, 0, stream>>>(src, dstp, cursor, esrc, E);

    dim3 ggrid((N + 63) / 64, 2);
    dim3 agrid((N + 1) / 2);

    // ---- layer 1 ----
    qkv_mfma_kernel<128><<<ggrid, 256, 0, stream>>>(xh, wfrag1, bq1, bk1, bv1, bs1,
                                                    qh, kv4, skip, N);
    attn_kernel<1><<<agrid, 128, 0, stream>>>(qh, kv4, off, esrc, skip, h1h, N);

    // ---- layer 2 ----
    qkv_mfma_kernel<32><<<ggrid, 256, 0, stream>>>((const ushort*)h1h, wfrag2, bq2, bk2, bv2, bs2,
                                                   qh, kv4, skip, N);
    attn_kernel<0><<<agrid, 128, 0, stream>>>(qh, kv4, off, esrc, skip, h2, N);

    // ---- pool + final linear ----
    pool_kernel<<<(N + 255) / 256, 256, 0, stream>>>(h2, batch, sums, cntf, N);
    final_lin_kernel<<<GG, 16, 0, stream>>>(sums, cntf, Wlin, blin, (float*)d_out);
}